// Round 1
// baseline (369.370 us; speedup 1.0000x reference)
//
#include <hip/hip_runtime.h>
#include <hip/hip_bf16.h>

#define B_N   512
#define L_N   200
#define E_N   128
#define D_N   384
#define K_N   384
#define M_PAD 208   // 13 tiles of 16 rows
#define MT_N  13
#define NT_W  3     // 3 N-tiles of 16 per wave (8 waves x 48 cols = 384)
#define NWAVE 8
#define KSTEP 12    // 384 / 32
#define STR   40    // LDS row stride (elements); 80B: 16B-aligned b128, <=2-way bank conflict

typedef __bf16 v8bf __attribute__((ext_vector_type(8)));
typedef float  v4f  __attribute__((ext_vector_type(4)));

__device__ __forceinline__ unsigned short f2bf(float f) {
    union { __bf16 b; unsigned short u; } cv;
    cv.b = (__bf16)f;   // RNE convert
    return cv.u;
}

__global__ __launch_bounds__(512, 2)
void code2vec_fused(const int* __restrict__ xs1, const int* __restrict__ ph1,
                    const int* __restrict__ xt1,
                    const int* __restrict__ xs2, const int* __restrict__ ph2,
                    const int* __restrict__ xt2,
                    const float* __restrict__ wemb, const float* __restrict__ pemb,
                    const float* __restrict__ W, const float* __restrict__ attn,
                    float* __restrict__ out)
{
    const int tid  = threadIdx.x;
    const int wv   = tid >> 6;     // wave 0..7
    const int lane = tid & 63;
    const int quad = lane >> 4;    // 0..3
    const int c    = lane & 15;
    const int b    = blockIdx.x;
    const int pass = blockIdx.y;

    const int* xs = pass ? xs2 : xs1;
    const int* ph = pass ? ph2 : ph1;
    const int* xt = pass ? xt2 : xt1;

    __shared__ unsigned short Alds[M_PAD * STR];  // ctx slice [m][k0..k0+31] bf16
    __shared__ unsigned short Blds[D_N * STR];    // W slice   [n][k0..k0+31] bf16
    __shared__ float sp[NWAVE][M_PAD];            // per-wave score partials
    __shared__ float alds[M_PAD];                 // scores -> softmax weights
    __shared__ int   ilds[3 * L_N];               // gather indices

    if (tid < L_N) {
        ilds[tid]           = xs[b * L_N + tid];
        ilds[L_N + tid]     = ph[b * L_N + tid];
        ilds[2 * L_N + tid] = xt[b * L_N + tid];
    }

    // H accumulators stay in registers: 13 M-tiles x 3 N-tiles x 4 f32 = 156 regs
    v4f acc[MT_N][NT_W];
    #pragma unroll
    for (int i = 0; i < MT_N; ++i)
        #pragma unroll
        for (int j = 0; j < NT_W; ++j)
            acc[i][j] = (v4f){0.f, 0.f, 0.f, 0.f};

    __syncthreads();

    for (int kk = 0; kk < KSTEP; ++kk) {
        const int k0  = kk * 32;
        const int seg = k0 >> 7;          // 0: word[xs], 1: path[ph], 2: word[xt]
        const int ko  = k0 & 127;
        const float* ebase = (seg == 1) ? pemb : wemb;
        const int*   idxp  = &ilds[seg * L_N];

        // stage A: 208 rows x 8 float4 = 1664 units
        #pragma unroll
        for (int i = 0; i < 4; ++i) {
            int u = i * 512 + tid;
            if (u < M_PAD * 8) {
                int m = u >> 3, j = u & 7;
                ushort4 v;
                if (m < L_N) {
                    const float4 f = *(const float4*)(ebase + (size_t)idxp[m] * E_N + ko + j * 4);
                    v.x = f2bf(f.x); v.y = f2bf(f.y); v.z = f2bf(f.z); v.w = f2bf(f.w);
                } else {
                    v.x = 0; v.y = 0; v.z = 0; v.w = 0;
                }
                *(ushort4*)&Alds[m * STR + j * 4] = v;
            }
        }
        // stage B: 384 rows x 8 float4 = 3072 units (W_fc is [n][k] row-major already)
        #pragma unroll
        for (int i = 0; i < 6; ++i) {
            int u = i * 512 + tid;
            int n = u >> 3, j = u & 7;
            const float4 f = *(const float4*)(W + n * K_N + k0 + j * 4);
            ushort4 v;
            v.x = f2bf(f.x); v.y = f2bf(f.y); v.z = f2bf(f.z); v.w = f2bf(f.w);
            *(ushort4*)&Blds[n * STR + j * 4] = v;
        }
        __syncthreads();

        v8bf bfrag[NT_W];
        #pragma unroll
        for (int nt = 0; nt < NT_W; ++nt) {
            int n = wv * 48 + nt * 16 + c;
            bfrag[nt] = *(const v8bf*)&Blds[n * STR + quad * 8];
        }
        #pragma unroll
        for (int mt = 0; mt < MT_N; ++mt) {
            v8bf afrag = *(const v8bf*)&Alds[(mt * 16 + c) * STR + quad * 8];
            #pragma unroll
            for (int nt = 0; nt < NT_W; ++nt)
                acc[mt][nt] = __builtin_amdgcn_mfma_f32_16x16x32_bf16(afrag, bfrag[nt], acc[mt][nt], 0, 0, 0);
        }
        __syncthreads();
    }

    // tanh in-register + score partials: s[m] = sum_n h[m][n]*attn[n]
    float an[NT_W];
    #pragma unroll
    for (int nt = 0; nt < NT_W; ++nt) an[nt] = attn[wv * 48 + nt * 16 + c];

    #pragma unroll
    for (int mt = 0; mt < MT_N; ++mt) {
        #pragma unroll
        for (int r = 0; r < 4; ++r) {
            float sv = 0.f;
            #pragma unroll
            for (int nt = 0; nt < NT_W; ++nt) {
                float h = tanhf(acc[mt][nt][r]);
                acc[mt][nt][r] = h;
                sv += h * an[nt];
            }
            sv += __shfl_xor(sv, 1);
            sv += __shfl_xor(sv, 2);
            sv += __shfl_xor(sv, 4);
            sv += __shfl_xor(sv, 8);
            if (c == 0) sp[wv][mt * 16 + quad * 4 + r] = sv;
        }
    }
    __syncthreads();

    // cross-wave sum of score partials
    if (tid < M_PAD) {
        float s = 0.f;
        #pragma unroll
        for (int w2 = 0; w2 < NWAVE; ++w2) s += sp[w2][tid];
        alds[tid] = s;  // pad rows (>=200) hold 0, excluded below
    }
    __syncthreads();

    // softmax over l in [0,200) by wave 0
    if (wv == 0) {
        float v0 = alds[lane];
        float v1 = alds[64 + lane];
        float v2 = alds[128 + lane];
        bool  has3 = (192 + lane) < L_N;
        float v3 = has3 ? alds[192 + lane] : -1e30f;
        float mx = fmaxf(fmaxf(v0, v1), fmaxf(v2, v3));
        #pragma unroll
        for (int off = 32; off > 0; off >>= 1) mx = fmaxf(mx, __shfl_xor(mx, off));
        float e0 = __expf(v0 - mx);
        float e1 = __expf(v1 - mx);
        float e2 = __expf(v2 - mx);
        float e3 = has3 ? __expf(v3 - mx) : 0.f;
        float z = e0 + e1 + e2 + e3;
        #pragma unroll
        for (int off = 32; off > 0; off >>= 1) z += __shfl_xor(z, off);
        float inv = 1.f / z;
        alds[lane]       = e0 * inv;
        alds[64 + lane]  = e1 * inv;
        alds[128 + lane] = e2 * inv;
        if (192 + lane < M_PAD) alds[192 + lane] = e3 * inv;  // pad rows -> 0
    }
    __syncthreads();

    // code_vec[n] = sum_m a[m] * h[m][n]; each wave owns its 48 columns
    float* outp = out + (size_t)pass * B_N * D_N + (size_t)b * D_N;
    #pragma unroll
    for (int nt = 0; nt < NT_W; ++nt) {
        float cv = 0.f;
        #pragma unroll
        for (int mt = 0; mt < MT_N; ++mt) {
            #pragma unroll
            for (int r = 0; r < 4; ++r)
                cv += alds[mt * 16 + quad * 4 + r] * acc[mt][nt][r];
        }
        cv += __shfl_xor(cv, 16);
        cv += __shfl_xor(cv, 32);
        if (quad == 0) outp[wv * 48 + nt * 16 + c] = cv;
    }
}

extern "C" void kernel_launch(void* const* d_in, const int* in_sizes, int n_in,
                              void* d_out, int out_size, void* d_ws, size_t ws_size,
                              hipStream_t stream) {
    dim3 grid(B_N, 2, 1);
    code2vec_fused<<<grid, 512, 0, stream>>>(
        (const int*)d_in[0], (const int*)d_in[1], (const int*)d_in[2],
        (const int*)d_in[3], (const int*)d_in[4], (const int*)d_in[5],
        (const float*)d_in[6], (const float*)d_in[7],
        (const float*)d_in[8], (const float*)d_in[9],
        (float*)d_out);
}

// Round 2
// 358.820 us; speedup vs baseline: 1.0294x; 1.0294x over previous
//
#include <hip/hip_runtime.h>
#include <hip/hip_bf16.h>

#define B_N   512
#define L_N   200
#define E_N   128
#define D_N   384
#define K_N   384
#define M_PAD 208   // 13 tiles of 16 rows
#define MT_N  13
#define NT_W  3     // 3 N-tiles of 16 per wave (8 waves x 48 cols = 384)
#define NWAVE 8
#define KSTEP 12    // 384 / 32
#define STR   136   // A LDS row stride (bf16 elems); 272B: 16B-aligned b128, 2-way banks (free)

typedef __bf16 v8bf  __attribute__((ext_vector_type(8)));
typedef float  v4f   __attribute__((ext_vector_type(4)));
typedef unsigned int v4u __attribute__((ext_vector_type(4)));

__device__ __forceinline__ unsigned short f2bf(float f) {
    union { __bf16 b; unsigned short u; } cv;
    cv.b = (__bf16)f;   // RNE convert
    return cv.u;
}

__device__ __forceinline__ float fast_tanh(float x) {
    float e = __expf(2.f * x);          // v_exp_f32 path
    return 1.f - 2.f / (e + 1.f);       // e=inf -> 1, e=0 -> -1
}

// Pack W_fc [384][384] f32 -> bf16 fragments in d_ws, ordered so the main
// kernel's wave reads its B fragment as one coalesced 16B/lane global load:
// gid = ((kk*8 + wv)*3 + nt)*64 + lane ; lane=(quad<<4)|c
// holds W[n = wv*48+nt*16+c][k = kk*32+quad*8 .. +7]
__global__ void pack_w(const float* __restrict__ W, unsigned short* __restrict__ Wp) {
    int gid  = blockIdx.x * 256 + threadIdx.x;      // 18432 threads
    int lane = gid & 63;
    int u    = gid >> 6;                            // [0,288)
    int nt   = u % 3;
    int wv   = (u / 3) & 7;
    int kk   = u / 24;
    int c    = lane & 15;
    int quad = lane >> 4;
    int n    = wv * 48 + nt * 16 + c;
    int k0   = kk * 32 + quad * 8;
    const float* src = W + n * K_N + k0;
    ushort4 lo, hi;
    lo.x = f2bf(src[0]); lo.y = f2bf(src[1]); lo.z = f2bf(src[2]); lo.w = f2bf(src[3]);
    hi.x = f2bf(src[4]); hi.y = f2bf(src[5]); hi.z = f2bf(src[6]); hi.w = f2bf(src[7]);
    ushort4* dst = (ushort4*)(Wp + (size_t)gid * 8);
    dst[0] = lo;
    dst[1] = hi;
}

__global__ __launch_bounds__(512, 2)
void code2vec_fused(const int* __restrict__ xs1, const int* __restrict__ ph1,
                    const int* __restrict__ xt1,
                    const int* __restrict__ xs2, const int* __restrict__ ph2,
                    const int* __restrict__ xt2,
                    const float* __restrict__ wemb, const float* __restrict__ pemb,
                    const unsigned short* __restrict__ Wp,
                    const float* __restrict__ attn,
                    float* __restrict__ out)
{
    const int tid  = threadIdx.x;
    const int wv   = tid >> 6;     // wave 0..7
    const int lane = tid & 63;
    const int quad = lane >> 4;    // 0..3
    const int c    = lane & 15;
    const int b    = blockIdx.x;
    const int pass = blockIdx.y;

    const int* xs = pass ? xs2 : xs1;
    const int* ph = pass ? ph2 : ph1;
    const int* xt = pass ? xt2 : xt1;

    __shared__ unsigned short Alds[M_PAD * STR];  // one 128-wide ctx segment, bf16
    __shared__ float sp[NWAVE][M_PAD];            // per-wave score partials
    __shared__ float alds[M_PAD];                 // scores -> softmax weights
    __shared__ int   ilds[3 * L_N];               // gather indices

    if (tid < L_N) {
        ilds[tid]           = xs[b * L_N + tid];
        ilds[L_N + tid]     = ph[b * L_N + tid];
        ilds[2 * L_N + tid] = xt[b * L_N + tid];
    }

    // H accumulators live in registers: 13 M-tiles x 3 N-tiles x 4 f32 = 156
    v4f acc[MT_N][NT_W];
    #pragma unroll
    for (int i = 0; i < MT_N; ++i)
        #pragma unroll
        for (int j = 0; j < NT_W; ++j)
            acc[i][j] = (v4f){0.f, 0.f, 0.f, 0.f};

    const v4u* wp4 = (const v4u*)Wp;

    for (int seg = 0; seg < 3; ++seg) {
        const float* ebase = (seg == 1) ? pemb : wemb;
        const int*   idxp  = &ilds[seg * L_N];

        __syncthreads();   // protect Alds from previous segment's readers (and ilds on seg 0)

        // stage full 128-wide segment: 208 rows x 16 chunks of 16B = 3328 units
        #pragma unroll
        for (int i = 0; i < 7; ++i) {
            int u = i * 512 + tid;
            if (u < M_PAD * 16) {
                int m = u >> 4, jj = u & 15;     // jj: 8-elem chunk
                ushort4 lo, hi;
                if (m < L_N) {
                    const float* src = ebase + (size_t)idxp[m] * E_N + jj * 8;
                    const float4 f0 = *(const float4*)(src);
                    const float4 f1 = *(const float4*)(src + 4);
                    lo.x = f2bf(f0.x); lo.y = f2bf(f0.y); lo.z = f2bf(f0.z); lo.w = f2bf(f0.w);
                    hi.x = f2bf(f1.x); hi.y = f2bf(f1.y); hi.z = f2bf(f1.z); hi.w = f2bf(f1.w);
                } else {
                    lo.x = lo.y = lo.z = lo.w = 0;
                    hi.x = hi.y = hi.z = hi.w = 0;
                }
                ushort4* dst = (ushort4*)&Alds[m * STR + jj * 8];
                dst[0] = lo;
                dst[1] = hi;
            }
        }
        __syncthreads();

        // 4 K-steps from this segment; B fragments straight from L2-resident Wp
        #pragma unroll
        for (int t = 0; t < 4; ++t) {
            const int kk = seg * 4 + t;
            v8bf bfrag[NT_W];
            #pragma unroll
            for (int nt = 0; nt < NT_W; ++nt) {
                v4u raw = wp4[((kk * NWAVE + wv) * NT_W + nt) * 64 + lane];
                bfrag[nt] = __builtin_bit_cast(v8bf, raw);
            }
            #pragma unroll
            for (int mt = 0; mt < MT_N; ++mt) {
                v8bf afrag = *(const v8bf*)&Alds[(mt * 16 + c) * STR + t * 32 + quad * 8];
                #pragma unroll
                for (int nt = 0; nt < NT_W; ++nt)
                    acc[mt][nt] = __builtin_amdgcn_mfma_f32_16x16x32_bf16(afrag, bfrag[nt], acc[mt][nt], 0, 0, 0);
            }
        }
    }

    // tanh in-register + score partials: s[m] = sum_n h[m][n]*attn[n]
    float an[NT_W];
    #pragma unroll
    for (int nt = 0; nt < NT_W; ++nt) an[nt] = attn[wv * 48 + nt * 16 + c];

    #pragma unroll
    for (int mt = 0; mt < MT_N; ++mt) {
        #pragma unroll
        for (int r = 0; r < 4; ++r) {
            float sv = 0.f;
            #pragma unroll
            for (int nt = 0; nt < NT_W; ++nt) {
                float h = fast_tanh(acc[mt][nt][r]);
                acc[mt][nt][r] = h;
                sv += h * an[nt];
            }
            sv += __shfl_xor(sv, 1);
            sv += __shfl_xor(sv, 2);
            sv += __shfl_xor(sv, 4);
            sv += __shfl_xor(sv, 8);
            if (c == 0) sp[wv][mt * 16 + quad * 4 + r] = sv;
        }
    }
    __syncthreads();

    // cross-wave sum of score partials
    if (tid < M_PAD) {
        float s = 0.f;
        #pragma unroll
        for (int w2 = 0; w2 < NWAVE; ++w2) s += sp[w2][tid];
        alds[tid] = s;  // pad rows (>=200) hold 0, excluded below
    }
    __syncthreads();

    // softmax over l in [0,200) by wave 0
    if (wv == 0) {
        float v0 = alds[lane];
        float v1 = alds[64 + lane];
        float v2 = alds[128 + lane];
        bool  has3 = (192 + lane) < L_N;
        float v3 = has3 ? alds[192 + lane] : -1e30f;
        float mx = fmaxf(fmaxf(v0, v1), fmaxf(v2, v3));
        #pragma unroll
        for (int off = 32; off > 0; off >>= 1) mx = fmaxf(mx, __shfl_xor(mx, off));
        float e0 = __expf(v0 - mx);
        float e1 = __expf(v1 - mx);
        float e2 = __expf(v2 - mx);
        float e3 = has3 ? __expf(v3 - mx) : 0.f;
        float z = e0 + e1 + e2 + e3;
        #pragma unroll
        for (int off = 32; off > 0; off >>= 1) z += __shfl_xor(z, off);
        float inv = 1.f / z;
        alds[lane]       = e0 * inv;
        alds[64 + lane]  = e1 * inv;
        alds[128 + lane] = e2 * inv;
        if (192 + lane < M_PAD) alds[192 + lane] = e3 * inv;  // pad rows -> 0
    }
    __syncthreads();

    // code_vec[n] = sum_m a[m] * h[m][n]; each wave owns its 48 columns
    float* outp = out + (size_t)pass * B_N * D_N + (size_t)b * D_N;
    #pragma unroll
    for (int nt = 0; nt < NT_W; ++nt) {
        float cv = 0.f;
        #pragma unroll
        for (int mt = 0; mt < MT_N; ++mt) {
            #pragma unroll
            for (int r = 0; r < 4; ++r)
                cv += alds[mt * 16 + quad * 4 + r] * acc[mt][nt][r];
        }
        cv += __shfl_xor(cv, 16);
        cv += __shfl_xor(cv, 32);
        if (quad == 0) outp[wv * 48 + nt * 16 + c] = cv;
    }
}

extern "C" void kernel_launch(void* const* d_in, const int* in_sizes, int n_in,
                              void* d_out, int out_size, void* d_ws, size_t ws_size,
                              hipStream_t stream) {
    unsigned short* Wp = (unsigned short*)d_ws;   // 294912 B
    pack_w<<<72, 256, 0, stream>>>((const float*)d_in[8], Wp);
    dim3 grid(B_N, 2, 1);
    code2vec_fused<<<grid, 512, 0, stream>>>(
        (const int*)d_in[0], (const int*)d_in[1], (const int*)d_in[2],
        (const int*)d_in[3], (const int*)d_in[4], (const int*)d_in[5],
        (const float*)d_in[6], (const float*)d_in[7],
        Wp, (const float*)d_in[9],
        (float*)d_out);
}